// Round 9
// baseline (211.187 us; speedup 1.0000x reference)
//
#include <hip/hip_runtime.h>

// B=4, N=10, C=256, Lq=Ls=1024, K=5, G=2.  TQ=64, TS=32.  fp16 MFMA path.
#define CQ_ELEMS (4 * 256 * 1024)
#define CS_ELEMS (10 * 256 * 1024)
#define OUT2_OFF 2097152

typedef __attribute__((ext_vector_type(8))) _Float16 f16x8;
typedef __attribute__((ext_vector_type(4))) float f32x4;

// ws layout (bytes): [0..255] float means[2];
//   Sh[n][s][c] fp16, Sv[n][c][s] fp16, Qt[b][q][c] fp16
#define WS_SH 256
#define SH_ELEMS (10 * 1024 * 256)
#define SV_ELEMS (10 * 256 * 1024)

// direct global->LDS DMA, 16 B per lane; LDS dest = wave-uniform base + lane*16
__device__ __forceinline__ void gload_lds16(const unsigned short* g, unsigned short* l) {
    __builtin_amdgcn_global_load_lds(
        (const __attribute__((address_space(1))) void*)g,
        (__attribute__((address_space(3))) void*)l, 16, 0, 0);
}

// ---------------------------------------------------------------------------
__global__ __launch_bounds__(256) void means_kernel(const float* __restrict__ q,
                                                    const float* __restrict__ s,
                                                    float* __restrict__ ws) {
    const int tid = blockIdx.x * 256 + threadIdx.x;
    const int stride = gridDim.x * 256;
    float sq = 0.f, ss = 0.f;
    const float4* q4 = (const float4*)q;
    const float4* s4 = (const float4*)s;
    for (int i = tid; i < CQ_ELEMS / 4; i += stride) {
        float4 v = q4[i];
        sq += (v.x + v.y) + (v.z + v.w);
    }
    for (int i = tid; i < CS_ELEMS / 4; i += stride) {
        float4 v = s4[i];
        ss += (v.x + v.y) + (v.z + v.w);
    }
#pragma unroll
    for (int off = 32; off > 0; off >>= 1) {
        sq += __shfl_down(sq, off, 64);
        ss += __shfl_down(ss, off, 64);
    }
    __shared__ float redq[4], reds[4];
    const int lane = threadIdx.x & 63, wid = threadIdx.x >> 6;
    if (lane == 0) { redq[wid] = sq; reds[wid] = ss; }
    __syncthreads();
    if (threadIdx.x == 0) {
        atomicAdd(&ws[0], (redq[0] + redq[1]) + (redq[2] + redq[3]));
        atomicAdd(&ws[1], (reds[0] + reds[1]) + (reds[2] + reds[3]));
    }
}

// ---------------------------------------------------------------------------
// Centered fp16 conversion.  z<10: S -> Sv [c][s] + Sh [s][c] + zero out2.
// z>=10: Q -> q_out (fp32, both g-copies) + Qt [q][c].
// ---------------------------------------------------------------------------
__global__ __launch_bounds__(256) void convert_kernel(const float* __restrict__ Q,
                                                      const float* __restrict__ S,
                                                      const float* __restrict__ ws,
                                                      unsigned short* __restrict__ sh,
                                                      unsigned short* __restrict__ sv,
                                                      unsigned short* __restrict__ qt,
                                                      float* __restrict__ out) {
    __shared__ unsigned short Th[32][40];
    const int t = threadIdx.x;
    const int x0 = blockIdx.x << 5;   // s (or q) tile base
    const int c0 = blockIdx.y << 5;   // c tile base
    const int z = blockIdx.z;

    const int cl = t >> 3, x4 = (t & 7) << 2;

    if (z < 10) {
        const int n = z;
        const float ms = ws[1] * (1.0f / (float)CS_ELEMS);
        float4 v = *(const float4*)(S + ((size_t)(n * 256 + c0 + cl)) * 1024 + x0 + x4);
        float x[4] = {v.x - ms, v.y - ms, v.z - ms, v.w - ms};
        unsigned short hb[4];
#pragma unroll
        for (int j = 0; j < 4; ++j) {
            _Float16 h = (_Float16)x[j];
            hb[j] = __builtin_bit_cast(unsigned short, h);
            Th[cl][x4 + j] = hb[j];
        }
        *(ushort4*)(sv + ((size_t)(n * 256 + c0 + cl)) * 1024 + x0 + x4) =
            make_ushort4(hb[0], hb[1], hb[2], hb[3]);
        // zero the atomically-accumulated 'aligned' half of d_out (8 MB over 2560 blocks)
        {
            const int lin = (z * 8 + blockIdx.y) * 32 + blockIdx.x;
            const int gid = lin * 256 + t;
            if (gid < 524288) ((int4*)(out + OUT2_OFF))[gid] = make_int4(0, 0, 0, 0);
        }
        __syncthreads();
        const int sl = t >> 3, c4 = (t & 7) << 2;
        *(ushort4*)(sh + ((size_t)(n * 1024 + x0 + sl)) * 256 + c0 + c4) =
            make_ushort4(Th[c4 + 0][sl], Th[c4 + 1][sl], Th[c4 + 2][sl], Th[c4 + 3][sl]);
    } else {
        const int b = z - 10;
        const float mq = ws[0] * (1.0f / (float)CQ_ELEMS);
        float4 v = *(const float4*)(Q + ((size_t)(b * 256 + c0 + cl)) * 1024 + x0 + x4);
        v.x -= mq; v.y -= mq; v.z -= mq; v.w -= mq;
        float* o = out + ((size_t)(b * 2) * 256 + (c0 + cl)) * 1024 + x0 + x4;
        *(float4*)o = v;
        *(float4*)(o + 256 * 1024) = v;
        float x[4] = {v.x, v.y, v.z, v.w};
#pragma unroll
        for (int j = 0; j < 4; ++j) {
            _Float16 h = (_Float16)x[j];
            Th[cl][x4 + j] = __builtin_bit_cast(unsigned short, h);
        }
        __syncthreads();
        const int ql = t >> 3, c4 = (t & 7) << 2;
        *(ushort4*)(qt + ((size_t)(b * 1024 + x0 + ql)) * 256 + c0 + c4) =
            make_ushort4(Th[c4 + 0][ql], Th[c4 + 1][ql], Th[c4 + 2][ql], Th[c4 + 3][ql]);
    }
}

// ---------------------------------------------------------------------------
// Fused flash attention, fp16 MFMA, DMA staging.  R7 (115 us) + counted-vmcnt
// barrier slimming.  Key facts:
//   * s2 (V) is per-wave PRIVATE (wave w stages exactly the groups it reads)
//     -> its readiness needs only a per-wave s_waitcnt vmcnt(0) before the vf
//     reads, placed AFTER softmax -> ~QK+softmax of latency cover.
//   * s1 (K) is cross-wave: each wave waits vmcnt(4) (its OWN s1 loads; the 4
//     s2 loads keep flying) BEFORE s_barrier -> at barrier-exit all 16 s1
//     groups have landed.  Barrier B no longer drains 32 KB.
//   * P-publish barrier is lgkmcnt(0)-only (LDS visibility; no vmem drain).
//   * sched_barrier(0) after every inline-asm wait (rule: compiler hoists
//     register-only MFMAs past asm waitcnt otherwise).
//   * setprio(1) around both MFMA clusters.
// Everything else (layouts, XCD swizzle, Lsum fold, epilogue) identical to R7.
//
// (1) XCD-affinity block swizzle: all 64 blocks sharing support-stream n land
//     on one XCD (FETCH 48.8 -> 16.4 MB, verified R7).
// (2) Row-sum folded into PV as a ones-channel MFMA (Lsum).
//
// s1 (16 KB): frag-major.  slot16 p = (f*2+nt)*64 + quad*16 + l16 holds
//   Sh[s0 + 2*l16 + nt][f*32 + quad*8 .. +7].
// s2 (16 KB): slot16 p holds V^T[c = p>>2][chunk = (p&3) ^ ((c>>2)&3)];
//   read p = c*4 + (quad ^ ((l16>>2)&3)) -> 2-way (free).
// pb: P [q][s] 80 B rows; alpha at cols 32-33.
// ---------------------------------------------------------------------------
union __align__(16) SMem {
    struct {
        unsigned short s1[8192];     // 16 KB
        unsigned short s2[8192];     // 16 KB
        unsigned short pb[64][40];   // 5 KB (cols 32-33: alpha float)
    } st;
    float epi[2][64][68];            // 34816 B, aliases s1+s2+pb[0..25] at epilogue
};

__global__ __launch_bounds__(256, 3) void attn_kernel(const unsigned short* __restrict__ qt,
                                                      const unsigned short* __restrict__ sh,
                                                      const unsigned short* __restrict__ sv,
                                                      float* __restrict__ out) {
    __shared__ SMem sm;

    const int t = threadIdx.x;
    const int w = t >> 6;
    const int lane = t & 63;
    const int quad = lane >> 4;
    const int l16 = lane & 15;

    // ---- XCD-affinity decode: all blocks of a given n on one XCD ----
    int qx, b, n;
    {
        const int L = blockIdx.x;          // 0..639
        if (L < 512) {
            n = L & 7;                     // XCD = L % 8 = n
            const int inner = L >> 3;      // 0..63
            b = inner & 3;
            qx = inner >> 2;               // 0..15
        } else {
            const int r = L - 512;         // 0..127
            const int x = r & 7;           // XCD
            n = 8 + (x >> 2);              // 8 on XCD 0-3, 9 on XCD 4-7
            const int combo = (x & 3) * 16 + (r >> 3);   // 0..63
            b = combo & 3;
            qx = combo >> 2;
        }
    }
    const int q0 = qx << 6;
    const int g = n / 5;

    const unsigned short* __restrict__ Shn = sh + (size_t)n * (1024 * 256);
    const unsigned short* __restrict__ Svn = sv + (size_t)n * (256 * 1024);

    // ---- Q A-frags: wave w owns q rows q0+16w .. +15 ----
    f16x8 qf[8];
    {
        const unsigned short* qp = qt + (size_t)(b * 1024 + q0 + 16 * w + l16) * 256 + quad * 8;
#pragma unroll
        for (int f = 0; f < 8; ++f)
            qf[f] = *(const f16x8*)(qp + f * 32);
    }

    // ones A-frag for the row-sum channel
    f16x8 onesA;
#pragma unroll
    for (int j = 0; j < 8; ++j) onesA[j] = (_Float16)1.0f;

    f32x4 O[4][4];   // O^T: c = 64w+16mt+4quad+r, q = 16nt+l16
#pragma unroll
    for (int mt = 0; mt < 4; ++mt)
#pragma unroll
        for (int nt = 0; nt < 4; ++nt) O[mt][nt] = (f32x4){0.f, 0.f, 0.f, 0.f};

    f32x4 Lsum[4];   // row-sum channel: Lsum[nt][*] = sum_s P[q=16nt+l16][s]
#pragma unroll
    for (int nt = 0; nt < 4; ++nt) Lsum[nt] = (f32x4){0.f, 0.f, 0.f, 0.f};

    float m_run[4];
#pragma unroll
    for (int r = 0; r < 4; ++r) m_run[r] = -1e30f;

    for (int s0i = 0; s0i < 32; ++s0i) {
        const int s0 = s0i << 5;
        __syncthreads();   // A: all waves done reading previous tiles / pb

        // ---- issue s1 (4 loads) THEN s2 (4 loads): vmcnt counting relies on order ----
#pragma unroll
        for (int j = 0; j < 4; ++j) {
            const int fidx = 4 * w + j;
            const unsigned short* g1 = Shn +
                (size_t)(s0 + 2 * (lane & 15) + (fidx & 1)) * 256 + (fidx >> 1) * 32 + (lane >> 4) * 8;
            gload_lds16(g1, &sm.st.s1[fidx * 512]);
        }
#pragma unroll
        for (int j = 0; j < 4; ++j) {
            const int fidx = 4 * w + j;
            const unsigned short* g2 = Svn +
                (size_t)(w * 64 + j * 16 + (lane >> 2)) * 1024 + s0 + ((lane & 3) ^ (lane >> 4)) * 8;
            gload_lds16(g2, &sm.st.s2[fidx * 512]);
        }

        // own s1 landed (s2 keeps flying); barrier-exit => ALL s1 groups landed
        asm volatile("s_waitcnt vmcnt(4)" ::: "memory");
        __builtin_amdgcn_s_barrier();   // B
        __builtin_amdgcn_sched_barrier(0);

        // ---- QK^T: sim[16q x 32s] ----
        f32x4 sim0 = (f32x4){0.f, 0.f, 0.f, 0.f};
        f32x4 sim1 = (f32x4){0.f, 0.f, 0.f, 0.f};
        __builtin_amdgcn_s_setprio(1);
#pragma unroll
        for (int f = 0; f < 8; ++f) {
            const unsigned short* base = &sm.st.s1[f * 1024 + quad * 128 + l16 * 8];
            f16x8 b0 = *(const f16x8*)base;           // nt=0: true s = 2*l16
            f16x8 b1 = *(const f16x8*)(base + 512);   // nt=1: true s = 2*l16+1
            sim0 = __builtin_amdgcn_mfma_f32_16x16x32_f16(qf[f], b0, sim0, 0, 0, 0);
            sim1 = __builtin_amdgcn_mfma_f32_16x16x32_f16(qf[f], b1, sim1, 0, 0, 0);
        }
        __builtin_amdgcn_s_setprio(0);

        // ---- online softmax, max only (rows q = 16w+4quad+r; reduce over l16) ----
        float rowmax[4];
#pragma unroll
        for (int r = 0; r < 4; ++r) rowmax[r] = fmaxf(sim0[r], sim1[r]);
#pragma unroll
        for (int off = 1; off <= 8; off <<= 1)
#pragma unroll
            for (int r = 0; r < 4; ++r)
                rowmax[r] = fmaxf(rowmax[r], __shfl_xor(rowmax[r], off, 64));

        float al[4], pv0[4], pv1[4];
#pragma unroll
        for (int r = 0; r < 4; ++r) {
            const float mn = fmaxf(m_run[r], rowmax[r]);
            al[r] = __expf(m_run[r] - mn);
            m_run[r] = mn;
            pv0[r] = __expf(sim0[r] - mn);
            pv1[r] = __expf(sim1[r] - mn);
        }

        // ---- publish P (fp16 pairs, b32) and alpha (pb cols 32-33) ----
#pragma unroll
        for (int r = 0; r < 4; ++r) {
            union { _Float16 h[2]; unsigned u; } pk;
            pk.h[0] = (_Float16)pv0[r];
            pk.h[1] = (_Float16)pv1[r];
            *(unsigned*)&sm.st.pb[16 * w + 4 * quad + r][l16 * 2] = pk.u;
        }
        if (l16 == 0) {
#pragma unroll
            for (int r = 0; r < 4; ++r)
                *(float*)&sm.st.pb[16 * w + 4 * quad + r][32] = al[r];
        }

        // LDS-visibility-only barrier: P ready; s2 DMA still in flight
        asm volatile("s_waitcnt lgkmcnt(0)" ::: "memory");
        __builtin_amdgcn_s_barrier();   // C
        __builtin_amdgcn_sched_barrier(0);

        // ---- rescale O^T and Lsum by alpha ----
#pragma unroll
        for (int nt = 0; nt < 4; ++nt) {
            const float a = *(const float*)&sm.st.pb[16 * nt + l16][32];
#pragma unroll
            for (int mt = 0; mt < 4; ++mt) {
                O[mt][nt][0] *= a; O[mt][nt][1] *= a; O[mt][nt][2] *= a; O[mt][nt][3] *= a;
            }
            Lsum[nt][0] *= a; Lsum[nt][1] *= a; Lsum[nt][2] *= a; Lsum[nt][3] *= a;
        }

        // own s2 landed (covered by QK+softmax+rescale)
        asm volatile("s_waitcnt vmcnt(0)" ::: "memory");
        __builtin_amdgcn_sched_barrier(0);

        // ---- O^T += V^T * P^T;  Lsum += ones * P^T ----
        f16x8 vf[4], pf[4];
#pragma unroll
        for (int mt = 0; mt < 4; ++mt) {
            const int c = 64 * w + 16 * mt + l16;
            const int p = c * 4 + (quad ^ ((l16 >> 2) & 3));
            vf[mt] = *(const f16x8*)&sm.st.s2[p * 8];
        }
#pragma unroll
        for (int nt = 0; nt < 4; ++nt)
            pf[nt] = *(const f16x8*)&sm.st.pb[16 * nt + l16][quad * 8];
        __builtin_amdgcn_s_setprio(1);
#pragma unroll
        for (int mt = 0; mt < 4; ++mt)
#pragma unroll
            for (int nt = 0; nt < 4; ++nt)
                O[mt][nt] = __builtin_amdgcn_mfma_f32_16x16x32_f16(vf[mt], pf[nt], O[mt][nt], 0, 0, 0);
#pragma unroll
        for (int nt = 0; nt < 4; ++nt)
            Lsum[nt] = __builtin_amdgcn_mfma_f32_16x16x32_f16(onesA, pf[nt], Lsum[nt], 0, 0, 0);
        __builtin_amdgcn_s_setprio(0);
    }

    // all final pb/s2 reads done before epi aliases them
    __syncthreads();

    // ---- epilogue: denominator in registers (Lsum), no LDS publish ----
    float linv[4];
#pragma unroll
    for (int nt = 0; nt < 4; ++nt)
        linv[nt] = 0.2f / Lsum[nt][0];

    float* __restrict__ out2 = out + OUT2_OFF + (size_t)((g << 2) + b) * (256 * 1024);

#pragma unroll
    for (int h = 0; h < 2; ++h) {
        if ((w >> 1) == h) {
            const int we = w & 1;
#pragma unroll
            for (int mt = 0; mt < 4; ++mt)
#pragma unroll
                for (int nt = 0; nt < 4; ++nt)
#pragma unroll
                    for (int r = 0; r < 4; ++r)
                        sm.epi[we][16 * mt + 4 * quad + r][16 * nt + l16] = O[mt][nt][r] * linv[nt];
        }
        __syncthreads();
#pragma unroll 4
        for (int i = 0; i < 32; ++i) {
            const int ro = w * 32 + i;   // 0..127 -> c = 128h + ro
            const float v = sm.epi[ro >> 6][ro & 63][lane];
            atomicAdd(out2 + (size_t)(h * 128 + ro) * 1024 + q0 + lane, v);
        }
        __syncthreads();
    }
}

// ---------------------------------------------------------------------------
extern "C" void kernel_launch(void* const* d_in, const int* in_sizes, int n_in,
                              void* d_out, int out_size, void* d_ws, size_t ws_size,
                              hipStream_t stream) {
    const float* q = (const float*)d_in[0];
    const float* s = (const float*)d_in[1];
    float* out = (float*)d_out;
    float* ws = (float*)d_ws;
    unsigned short* sh = (unsigned short*)((char*)d_ws + WS_SH);
    unsigned short* sv = sh + SH_ELEMS;
    unsigned short* qt = sv + SV_ELEMS;

    hipMemsetAsync(d_ws, 0, 2 * sizeof(float), stream);

    means_kernel<<<256, 256, 0, stream>>>(q, s, ws);
    convert_kernel<<<dim3(32, 8, 14), 256, 0, stream>>>(q, s, ws, sh, sv, qt, out);
    attn_kernel<<<640, 256, 0, stream>>>(qt, sh, sv, out);
}

// Round 10
// 189.661 us; speedup vs baseline: 1.1135x; 1.1135x over previous
//
#include <hip/hip_runtime.h>

// B=4, N=10, C=256, Lq=Ls=1024, K=5, G=2.  TQ=64, TS=32.  fp16 MFMA path.
#define CQ_ELEMS (4 * 256 * 1024)
#define CS_ELEMS (10 * 256 * 1024)
#define OUT2_OFF 2097152

typedef __attribute__((ext_vector_type(8))) _Float16 f16x8;
typedef __attribute__((ext_vector_type(4))) float f32x4;

// ws layout (bytes): [0..255] float means[2];
//   Sh[n][s][c] fp16, Sv[n][c][s] fp16, Qt[b][q][c] fp16
#define WS_SH 256
#define SH_ELEMS (10 * 1024 * 256)
#define SV_ELEMS (10 * 256 * 1024)

// direct global->LDS DMA, 16 B per lane; LDS dest = wave-uniform base + lane*16
__device__ __forceinline__ void gload_lds16(const unsigned short* g, unsigned short* l) {
    __builtin_amdgcn_global_load_lds(
        (const __attribute__((address_space(1))) void*)g,
        (__attribute__((address_space(3))) void*)l, 16, 0, 0);
}

// ---------------------------------------------------------------------------
__global__ __launch_bounds__(256) void means_kernel(const float* __restrict__ q,
                                                    const float* __restrict__ s,
                                                    float* __restrict__ ws) {
    const int tid = blockIdx.x * 256 + threadIdx.x;
    const int stride = gridDim.x * 256;
    float sq = 0.f, ss = 0.f;
    const float4* q4 = (const float4*)q;
    const float4* s4 = (const float4*)s;
    for (int i = tid; i < CQ_ELEMS / 4; i += stride) {
        float4 v = q4[i];
        sq += (v.x + v.y) + (v.z + v.w);
    }
    for (int i = tid; i < CS_ELEMS / 4; i += stride) {
        float4 v = s4[i];
        ss += (v.x + v.y) + (v.z + v.w);
    }
#pragma unroll
    for (int off = 32; off > 0; off >>= 1) {
        sq += __shfl_down(sq, off, 64);
        ss += __shfl_down(ss, off, 64);
    }
    __shared__ float redq[4], reds[4];
    const int lane = threadIdx.x & 63, wid = threadIdx.x >> 6;
    if (lane == 0) { redq[wid] = sq; reds[wid] = ss; }
    __syncthreads();
    if (threadIdx.x == 0) {
        atomicAdd(&ws[0], (redq[0] + redq[1]) + (redq[2] + redq[3]));
        atomicAdd(&ws[1], (reds[0] + reds[1]) + (reds[2] + reds[3]));
    }
}

// ---------------------------------------------------------------------------
// Centered fp16 conversion.  z<10: S -> Sv [c][s] + Sh [s][c] + zero out2.
// z>=10: Q -> q_out (fp32, both g-copies) + Qt [q][c].
// ---------------------------------------------------------------------------
__global__ __launch_bounds__(256) void convert_kernel(const float* __restrict__ Q,
                                                      const float* __restrict__ S,
                                                      const float* __restrict__ ws,
                                                      unsigned short* __restrict__ sh,
                                                      unsigned short* __restrict__ sv,
                                                      unsigned short* __restrict__ qt,
                                                      float* __restrict__ out) {
    __shared__ unsigned short Th[32][40];
    const int t = threadIdx.x;
    const int x0 = blockIdx.x << 5;   // s (or q) tile base
    const int c0 = blockIdx.y << 5;   // c tile base
    const int z = blockIdx.z;

    const int cl = t >> 3, x4 = (t & 7) << 2;

    if (z < 10) {
        const int n = z;
        const float ms = ws[1] * (1.0f / (float)CS_ELEMS);
        float4 v = *(const float4*)(S + ((size_t)(n * 256 + c0 + cl)) * 1024 + x0 + x4);
        float x[4] = {v.x - ms, v.y - ms, v.z - ms, v.w - ms};
        unsigned short hb[4];
#pragma unroll
        for (int j = 0; j < 4; ++j) {
            _Float16 h = (_Float16)x[j];
            hb[j] = __builtin_bit_cast(unsigned short, h);
            Th[cl][x4 + j] = hb[j];
        }
        *(ushort4*)(sv + ((size_t)(n * 256 + c0 + cl)) * 1024 + x0 + x4) =
            make_ushort4(hb[0], hb[1], hb[2], hb[3]);
        // zero the atomically-accumulated 'aligned' half of d_out (8 MB over 2560 blocks)
        {
            const int lin = (z * 8 + blockIdx.y) * 32 + blockIdx.x;
            const int gid = lin * 256 + t;
            if (gid < 524288) ((int4*)(out + OUT2_OFF))[gid] = make_int4(0, 0, 0, 0);
        }
        __syncthreads();
        const int sl = t >> 3, c4 = (t & 7) << 2;
        *(ushort4*)(sh + ((size_t)(n * 1024 + x0 + sl)) * 256 + c0 + c4) =
            make_ushort4(Th[c4 + 0][sl], Th[c4 + 1][sl], Th[c4 + 2][sl], Th[c4 + 3][sl]);
    } else {
        const int b = z - 10;
        const float mq = ws[0] * (1.0f / (float)CQ_ELEMS);
        float4 v = *(const float4*)(Q + ((size_t)(b * 256 + c0 + cl)) * 1024 + x0 + x4);
        v.x -= mq; v.y -= mq; v.z -= mq; v.w -= mq;
        float* o = out + ((size_t)(b * 2) * 256 + (c0 + cl)) * 1024 + x0 + x4;
        *(float4*)o = v;
        *(float4*)(o + 256 * 1024) = v;
        float x[4] = {v.x, v.y, v.z, v.w};
#pragma unroll
        for (int j = 0; j < 4; ++j) {
            _Float16 h = (_Float16)x[j];
            Th[cl][x4 + j] = __builtin_bit_cast(unsigned short, h);
        }
        __syncthreads();
        const int ql = t >> 3, c4 = (t & 7) << 2;
        *(ushort4*)(qt + ((size_t)(b * 1024 + x0 + ql)) * 256 + c0 + c4) =
            make_ushort4(Th[c4 + 0][ql], Th[c4 + 1][ql], Th[c4 + 2][ql], Th[c4 + 3][ql]);
    }
}

// ---------------------------------------------------------------------------
// Fused flash attention, fp16 MFMA, DMA staging.  = R7 (115 us, verified)
// with the REDUNDANT top-of-loop barrier removed: 2 x __syncthreads per
// iteration instead of 3.  Plain __syncthreads only -- every counted-vmcnt /
// raw-barrier / setprio variant regressed (R3 +56%, R9 +17%).
//
// Barrier-removal proof:
//   * s1 (K, cross-wave): QK reads(t) < C(t) < DMA writes(t+1); DMA
//     writes(t+1) < B(t+1) < QK reads(t+1).  B drains vmem (compiler emits
//     vmcnt(0) before s_barrier).
//   * pb (P/alpha, cross-wave): PV reads(t) < B(t+1) < softmax writes(t+1)
//     (each wave finishes PV before reaching B; writes happen after B).
//   * s2 (V): per-wave private (wave w writes AND reads only its quarter);
//     own-wave ds_read->MFMA completes (lgkmcnt) before next DMA issue.
//
// (1) XCD-affinity block swizzle: all 64 blocks sharing support-stream n land
//     on one XCD (FETCH 48.8 -> 16.4 MB, verified R7).
// (2) Row-sum folded into PV as a ones-channel MFMA (Lsum).
//
// s1 (16 KB): frag-major.  slot16 p = (f*2+nt)*64 + quad*16 + l16 holds
//   Sh[s0 + 2*l16 + nt][f*32 + quad*8 .. +7].
// s2 (16 KB): slot16 p holds V^T[c = p>>2][chunk = (p&3) ^ ((c>>2)&3)];
//   read p = c*4 + (quad ^ ((l16>>2)&3)) -> 2-way (free).
// pb: P [q][s] 80 B rows; alpha at cols 32-33.
// ---------------------------------------------------------------------------
union __align__(16) SMem {
    struct {
        unsigned short s1[8192];     // 16 KB
        unsigned short s2[8192];     // 16 KB
        unsigned short pb[64][40];   // 5 KB (cols 32-33: alpha float)
    } st;
    float epi[2][64][68];            // 34816 B, aliases s1+s2+pb[0..25] at epilogue
};

__global__ __launch_bounds__(256, 3) void attn_kernel(const unsigned short* __restrict__ qt,
                                                      const unsigned short* __restrict__ sh,
                                                      const unsigned short* __restrict__ sv,
                                                      float* __restrict__ out) {
    __shared__ SMem sm;

    const int t = threadIdx.x;
    const int w = t >> 6;
    const int lane = t & 63;
    const int quad = lane >> 4;
    const int l16 = lane & 15;

    // ---- XCD-affinity decode: all blocks of a given n on one XCD ----
    int qx, b, n;
    {
        const int L = blockIdx.x;          // 0..639
        if (L < 512) {
            n = L & 7;                     // XCD = L % 8 = n
            const int inner = L >> 3;      // 0..63
            b = inner & 3;
            qx = inner >> 2;               // 0..15
        } else {
            const int r = L - 512;         // 0..127
            const int x = r & 7;           // XCD
            n = 8 + (x >> 2);              // 8 on XCD 0-3, 9 on XCD 4-7
            const int combo = (x & 3) * 16 + (r >> 3);   // 0..63
            b = combo & 3;
            qx = combo >> 2;
        }
    }
    const int q0 = qx << 6;
    const int g = n / 5;

    const unsigned short* __restrict__ Shn = sh + (size_t)n * (1024 * 256);
    const unsigned short* __restrict__ Svn = sv + (size_t)n * (256 * 1024);

    // ---- Q A-frags: wave w owns q rows q0+16w .. +15 ----
    f16x8 qf[8];
    {
        const unsigned short* qp = qt + (size_t)(b * 1024 + q0 + 16 * w + l16) * 256 + quad * 8;
#pragma unroll
        for (int f = 0; f < 8; ++f)
            qf[f] = *(const f16x8*)(qp + f * 32);
    }

    // ones A-frag for the row-sum channel
    f16x8 onesA;
#pragma unroll
    for (int j = 0; j < 8; ++j) onesA[j] = (_Float16)1.0f;

    f32x4 O[4][4];   // O^T: c = 64w+16mt+4quad+r, q = 16nt+l16
#pragma unroll
    for (int mt = 0; mt < 4; ++mt)
#pragma unroll
        for (int nt = 0; nt < 4; ++nt) O[mt][nt] = (f32x4){0.f, 0.f, 0.f, 0.f};

    f32x4 Lsum[4];   // row-sum channel: Lsum[nt][*] = sum_s P[q=16nt+l16][s]
#pragma unroll
    for (int nt = 0; nt < 4; ++nt) Lsum[nt] = (f32x4){0.f, 0.f, 0.f, 0.f};

    float m_run[4];
#pragma unroll
    for (int r = 0; r < 4; ++r) m_run[r] = -1e30f;

    for (int s0i = 0; s0i < 32; ++s0i) {
        const int s0 = s0i << 5;

        // ---- DMA-stage s1 and s2 (wave w: 4 groups of 64 slots each).
        //      Safe without a top barrier: see dependency proof above. ----
#pragma unroll
        for (int j = 0; j < 4; ++j) {
            const int fidx = 4 * w + j;
            const unsigned short* g1 = Shn +
                (size_t)(s0 + 2 * (lane & 15) + (fidx & 1)) * 256 + (fidx >> 1) * 32 + (lane >> 4) * 8;
            gload_lds16(g1, &sm.st.s1[fidx * 512]);
            const unsigned short* g2 = Svn +
                (size_t)(w * 64 + j * 16 + (lane >> 2)) * 1024 + s0 + ((lane & 3) ^ (lane >> 4)) * 8;
            gload_lds16(g2, &sm.st.s2[fidx * 512]);
        }
        __syncthreads();   // B: drains vmcnt -> tiles ready; also fences pb(t) reads vs writes

        // ---- QK^T: sim[16q x 32s] ----
        f32x4 sim0 = (f32x4){0.f, 0.f, 0.f, 0.f};
        f32x4 sim1 = (f32x4){0.f, 0.f, 0.f, 0.f};
#pragma unroll
        for (int f = 0; f < 8; ++f) {
            const unsigned short* base = &sm.st.s1[f * 1024 + quad * 128 + l16 * 8];
            f16x8 b0 = *(const f16x8*)base;           // nt=0: true s = 2*l16
            f16x8 b1 = *(const f16x8*)(base + 512);   // nt=1: true s = 2*l16+1
            sim0 = __builtin_amdgcn_mfma_f32_16x16x32_f16(qf[f], b0, sim0, 0, 0, 0);
            sim1 = __builtin_amdgcn_mfma_f32_16x16x32_f16(qf[f], b1, sim1, 0, 0, 0);
        }

        // ---- online softmax, max only (rows q = 16w+4quad+r; reduce over l16) ----
        float rowmax[4];
#pragma unroll
        for (int r = 0; r < 4; ++r) rowmax[r] = fmaxf(sim0[r], sim1[r]);
#pragma unroll
        for (int off = 1; off <= 8; off <<= 1)
#pragma unroll
            for (int r = 0; r < 4; ++r)
                rowmax[r] = fmaxf(rowmax[r], __shfl_xor(rowmax[r], off, 64));

        float al[4], pv0[4], pv1[4];
#pragma unroll
        for (int r = 0; r < 4; ++r) {
            const float mn = fmaxf(m_run[r], rowmax[r]);
            al[r] = __expf(m_run[r] - mn);
            m_run[r] = mn;
            pv0[r] = __expf(sim0[r] - mn);
            pv1[r] = __expf(sim1[r] - mn);
        }

        // ---- publish P (fp16 pairs, b32) and alpha (pb cols 32-33) ----
#pragma unroll
        for (int r = 0; r < 4; ++r) {
            union { _Float16 h[2]; unsigned u; } pk;
            pk.h[0] = (_Float16)pv0[r];
            pk.h[1] = (_Float16)pv1[r];
            *(unsigned*)&sm.st.pb[16 * w + 4 * quad + r][l16 * 2] = pk.u;
        }
        if (l16 == 0) {
#pragma unroll
            for (int r = 0; r < 4; ++r)
                *(float*)&sm.st.pb[16 * w + 4 * quad + r][32] = al[r];
        }
        __syncthreads();   // C: P ready

        // ---- rescale O^T and Lsum, then O^T += V^T * P^T; Lsum += ones * P^T ----
#pragma unroll
        for (int nt = 0; nt < 4; ++nt) {
            const float a = *(const float*)&sm.st.pb[16 * nt + l16][32];
#pragma unroll
            for (int mt = 0; mt < 4; ++mt) {
                O[mt][nt][0] *= a; O[mt][nt][1] *= a; O[mt][nt][2] *= a; O[mt][nt][3] *= a;
            }
            Lsum[nt][0] *= a; Lsum[nt][1] *= a; Lsum[nt][2] *= a; Lsum[nt][3] *= a;
        }
        f16x8 vf[4], pf[4];
#pragma unroll
        for (int mt = 0; mt < 4; ++mt) {
            const int c = 64 * w + 16 * mt + l16;
            const int p = c * 4 + (quad ^ ((l16 >> 2) & 3));
            vf[mt] = *(const f16x8*)&sm.st.s2[p * 8];
        }
#pragma unroll
        for (int nt = 0; nt < 4; ++nt)
            pf[nt] = *(const f16x8*)&sm.st.pb[16 * nt + l16][quad * 8];
#pragma unroll
        for (int mt = 0; mt < 4; ++mt)
#pragma unroll
            for (int nt = 0; nt < 4; ++nt)
                O[mt][nt] = __builtin_amdgcn_mfma_f32_16x16x32_f16(vf[mt], pf[nt], O[mt][nt], 0, 0, 0);
#pragma unroll
        for (int nt = 0; nt < 4; ++nt)
            Lsum[nt] = __builtin_amdgcn_mfma_f32_16x16x32_f16(onesA, pf[nt], Lsum[nt], 0, 0, 0);
    }

    // all final pb/s2 reads done before epi aliases them
    __syncthreads();

    // ---- epilogue: denominator in registers (Lsum), no LDS publish ----
    float linv[4];
#pragma unroll
    for (int nt = 0; nt < 4; ++nt)
        linv[nt] = 0.2f / Lsum[nt][0];

    float* __restrict__ out2 = out + OUT2_OFF + (size_t)((g << 2) + b) * (256 * 1024);

#pragma unroll
    for (int h = 0; h < 2; ++h) {
        if ((w >> 1) == h) {
            const int we = w & 1;
#pragma unroll
            for (int mt = 0; mt < 4; ++mt)
#pragma unroll
                for (int nt = 0; nt < 4; ++nt)
#pragma unroll
                    for (int r = 0; r < 4; ++r)
                        sm.epi[we][16 * mt + 4 * quad + r][16 * nt + l16] = O[mt][nt][r] * linv[nt];
        }
        __syncthreads();
#pragma unroll 4
        for (int i = 0; i < 32; ++i) {
            const int ro = w * 32 + i;   // 0..127 -> c = 128h + ro
            const float v = sm.epi[ro >> 6][ro & 63][lane];
            atomicAdd(out2 + (size_t)(h * 128 + ro) * 1024 + q0 + lane, v);
        }
        __syncthreads();
    }
}

// ---------------------------------------------------------------------------
extern "C" void kernel_launch(void* const* d_in, const int* in_sizes, int n_in,
                              void* d_out, int out_size, void* d_ws, size_t ws_size,
                              hipStream_t stream) {
    const float* q = (const float*)d_in[0];
    const float* s = (const float*)d_in[1];
    float* out = (float*)d_out;
    float* ws = (float*)d_ws;
    unsigned short* sh = (unsigned short*)((char*)d_ws + WS_SH);
    unsigned short* sv = sh + SH_ELEMS;
    unsigned short* qt = sv + SV_ELEMS;

    hipMemsetAsync(d_ws, 0, 2 * sizeof(float), stream);

    means_kernel<<<256, 256, 0, stream>>>(q, s, ws);
    convert_kernel<<<dim3(32, 8, 14), 256, 0, stream>>>(q, s, ws, sh, sv, qt, out);
    attn_kernel<<<640, 256, 0, stream>>>(qt, sh, sv, out);
}